// Round 1
// baseline (2591.926 us; speedup 1.0000x reference)
//
#include <hip/hip_runtime.h>
#include <math.h>

#define NN 100000
#define CC 128
#define EE 1600000
#define TM 32   // rows per MLP block; 100000 = 3125 * 32 exactly

// ---------------------------------------------------------------------------
// Scatter-add aggregation: agg[dst] += x[src], one (edge, channel) per thread.
// agg must be pre-initialized to x (so result is x + sum of neighbors).
// ---------------------------------------------------------------------------
__global__ void __launch_bounds__(256) scatter_add_kernel(
    const float* __restrict__ x, const int* __restrict__ src,
    const int* __restrict__ dst, float* __restrict__ agg)
{
    int t = blockIdx.x * 256 + threadIdx.x;
    int c = t & (CC - 1);
    int e = t >> 7;
    if (e < EE) {
        int s = src[e];
        int d = dst[e];
        atomicAdd(&agg[d * CC + c], x[s * CC + c]);
    }
}

// ---------------------------------------------------------------------------
// Fused GIN MLP: hout = elu( relu( hin @ wa + ba ) @ wb + bb )
// One block = TM rows. LDS tiles stored transposed [k][row] (+1 pad).
// Thread layout: 256 threads = 32 col-groups x 8 row-groups, 4x4 register tile.
// ---------------------------------------------------------------------------
__global__ void __launch_bounds__(256) mlp_kernel(
    const float* __restrict__ hin,
    const float* __restrict__ wa, const float* __restrict__ ba,
    const float* __restrict__ wb, const float* __restrict__ bb,
    float* __restrict__ hout)
{
    __shared__ float At[CC][TM + 1];
    __shared__ float Tt[CC][TM + 1];

    const int tid  = threadIdx.x;
    const int row0 = blockIdx.x * TM;

    // load input tile (coalesced global read, transposed LDS write)
    for (int idx = tid; idx < TM * CC; idx += 256) {
        int r = idx >> 7;          // row within tile
        int k = idx & (CC - 1);    // channel
        At[k][r] = hin[(row0 + r) * CC + k];
    }
    __syncthreads();

    const int cg = tid & 31;
    const int rg = tid >> 5;
    const int c0 = cg * 4;
    const int r0 = rg * 4;

    float acc[4][4];
#pragma unroll
    for (int i = 0; i < 4; ++i)
#pragma unroll
        for (int j = 0; j < 4; ++j) acc[i][j] = 0.f;

    // ---- stage 1: T = relu(A @ wa + ba) ----
#pragma unroll 4
    for (int k = 0; k < CC; ++k) {
        const float4 w = *(const float4*)&wa[k * CC + c0];
        const float a0 = At[k][r0 + 0];
        const float a1 = At[k][r0 + 1];
        const float a2 = At[k][r0 + 2];
        const float a3 = At[k][r0 + 3];
        acc[0][0] += a0 * w.x; acc[0][1] += a0 * w.y; acc[0][2] += a0 * w.z; acc[0][3] += a0 * w.w;
        acc[1][0] += a1 * w.x; acc[1][1] += a1 * w.y; acc[1][2] += a1 * w.z; acc[1][3] += a1 * w.w;
        acc[2][0] += a2 * w.x; acc[2][1] += a2 * w.y; acc[2][2] += a2 * w.z; acc[2][3] += a2 * w.w;
        acc[3][0] += a3 * w.x; acc[3][1] += a3 * w.y; acc[3][2] += a3 * w.z; acc[3][3] += a3 * w.w;
    }
    {
        const float4 bias = *(const float4*)&ba[c0];
#pragma unroll
        for (int r = 0; r < 4; ++r) {
            Tt[c0 + 0][r0 + r] = fmaxf(acc[r][0] + bias.x, 0.f);
            Tt[c0 + 1][r0 + r] = fmaxf(acc[r][1] + bias.y, 0.f);
            Tt[c0 + 2][r0 + r] = fmaxf(acc[r][2] + bias.z, 0.f);
            Tt[c0 + 3][r0 + r] = fmaxf(acc[r][3] + bias.w, 0.f);
        }
    }
    __syncthreads();

    // ---- stage 2: out = elu(T @ wb + bb) ----
#pragma unroll
    for (int i = 0; i < 4; ++i)
#pragma unroll
        for (int j = 0; j < 4; ++j) acc[i][j] = 0.f;

#pragma unroll 4
    for (int k = 0; k < CC; ++k) {
        const float4 w = *(const float4*)&wb[k * CC + c0];
        const float a0 = Tt[k][r0 + 0];
        const float a1 = Tt[k][r0 + 1];
        const float a2 = Tt[k][r0 + 2];
        const float a3 = Tt[k][r0 + 3];
        acc[0][0] += a0 * w.x; acc[0][1] += a0 * w.y; acc[0][2] += a0 * w.z; acc[0][3] += a0 * w.w;
        acc[1][0] += a1 * w.x; acc[1][1] += a1 * w.y; acc[1][2] += a1 * w.z; acc[1][3] += a1 * w.w;
        acc[2][0] += a2 * w.x; acc[2][1] += a2 * w.y; acc[2][2] += a2 * w.z; acc[2][3] += a2 * w.w;
        acc[3][0] += a3 * w.x; acc[3][1] += a3 * w.y; acc[3][2] += a3 * w.z; acc[3][3] += a3 * w.w;
    }
    {
        const float4 bias = *(const float4*)&bb[c0];
#pragma unroll
        for (int r = 0; r < 4; ++r) {
            float v0 = acc[r][0] + bias.x;
            float v1 = acc[r][1] + bias.y;
            float v2 = acc[r][2] + bias.z;
            float v3 = acc[r][3] + bias.w;
            float4 o;
            o.x = v0 > 0.f ? v0 : expm1f(v0);
            o.y = v1 > 0.f ? v1 : expm1f(v1);
            o.z = v2 > 0.f ? v2 : expm1f(v2);
            o.w = v3 > 0.f ? v3 : expm1f(v3);
            *(float4*)&hout[(row0 + r0 + r) * CC + c0] = o;
        }
    }
}

// ---------------------------------------------------------------------------
// Final head: out[i] = sigmoid(dot(h[i], lin_w) + lin_b). One wave per node.
// ---------------------------------------------------------------------------
__global__ void __launch_bounds__(256) final_kernel(
    const float* __restrict__ h, const float* __restrict__ lin_w,
    const float* __restrict__ lin_b, float* __restrict__ out)
{
    int wave = (blockIdx.x * 256 + threadIdx.x) >> 6;
    int lane = threadIdx.x & 63;
    if (wave >= NN) return;
    const float2 v = *(const float2*)&h[wave * CC + lane * 2];
    const float2 w = *(const float2*)&lin_w[lane * 2];
    float s = v.x * w.x + v.y * w.y;
#pragma unroll
    for (int off = 32; off > 0; off >>= 1) s += __shfl_down(s, off);
    if (lane == 0) {
        float z = s + lin_b[0];
        out[wave] = 1.f / (1.f + expf(-z));
    }
}

extern "C" void kernel_launch(void* const* d_in, const int* in_sizes, int n_in,
                              void* d_out, int out_size, void* d_ws, size_t ws_size,
                              hipStream_t stream) {
    const float* x   = (const float*)d_in[0];
    const int*   ei  = (const int*)d_in[1];      // [2][E]: row0=src, row1=dst
    const int*   src = ei;
    const int*   dst = ei + EE;
    const float* w0a = (const float*)d_in[2];
    const float* b0a = (const float*)d_in[3];
    const float* w0b = (const float*)d_in[4];
    const float* b0b = (const float*)d_in[5];
    const float* w1a = (const float*)d_in[6];
    const float* b1a = (const float*)d_in[7];
    const float* w1b = (const float*)d_in[8];
    const float* b1b = (const float*)d_in[9];
    const float* w2a = (const float*)d_in[10];
    const float* b2a = (const float*)d_in[11];
    const float* w2b = (const float*)d_in[12];
    const float* b2b = (const float*)d_in[13];
    const float* lw  = (const float*)d_in[14];
    const float* lb  = (const float*)d_in[15];
    float* outp = (float*)d_out;

    float* bufA = (float*)d_ws;            // agg / h1  (N*CC floats)
    float* bufB = bufA + (size_t)NN * CC;  // layer output

    const size_t actBytes = (size_t)NN * CC * sizeof(float);
    const int scatterBlocks = (EE * CC) / 256;   // 800000
    const int mlpBlocks = NN / TM;               // 3125
    const int finalBlocks = (NN * 64) / 256;     // 25000

    // ---- layer 1 ----
    hipMemcpyAsync(bufA, x, actBytes, hipMemcpyDeviceToDevice, stream);
    scatter_add_kernel<<<scatterBlocks, 256, 0, stream>>>(x, src, dst, bufA);
    mlp_kernel<<<mlpBlocks, 256, 0, stream>>>(bufA, w0a, b0a, w0b, b0b, bufB);

    // ---- layer 2 ----
    hipMemcpyAsync(bufA, bufB, actBytes, hipMemcpyDeviceToDevice, stream);
    scatter_add_kernel<<<scatterBlocks, 256, 0, stream>>>(bufB, src, dst, bufA);
    mlp_kernel<<<mlpBlocks, 256, 0, stream>>>(bufA, w1a, b1a, w1b, b1b, bufB);

    // ---- layer 3 ----
    hipMemcpyAsync(bufA, bufB, actBytes, hipMemcpyDeviceToDevice, stream);
    scatter_add_kernel<<<scatterBlocks, 256, 0, stream>>>(bufB, src, dst, bufA);
    mlp_kernel<<<mlpBlocks, 256, 0, stream>>>(bufA, w2a, b2a, w2b, b2b, bufB);

    // ---- head ----
    final_kernel<<<finalBlocks, 256, 0, stream>>>(bufB, lw, lb, outp);
}

// Round 2
// 1064.342 us; speedup vs baseline: 2.4352x; 2.4352x over previous
//
#include <hip/hip_runtime.h>
#include <math.h>

#define NN 100000
#define CC 128
#define EE 1600000
#define TM 32            // rows per MLP block; 100000 = 3125 * 32 exactly
#define SCAN_CHUNK 2048  // elements per scan block
#define NB_SCAN ((NN + SCAN_CHUNK - 1) / SCAN_CHUNK)  // 49

// ===========================================================================
// CSR build: deg histogram -> exclusive scan (3 kernels) -> fill col indices
// ===========================================================================
__global__ void __launch_bounds__(256) hist_kernel(
    const int* __restrict__ dst, int* __restrict__ deg)
{
    int e = blockIdx.x * 256 + threadIdx.x;
    if (e < EE) atomicAdd(&deg[dst[e]], 1);
}

__global__ void __launch_bounds__(256) deg_block_reduce(
    const int* __restrict__ deg, int* __restrict__ blockSums)
{
    int base = blockIdx.x * SCAN_CHUNK + threadIdx.x * 8;
    int s = 0;
#pragma unroll
    for (int i = 0; i < 8; ++i) {
        int idx = base + i;
        if (idx < NN) s += deg[idx];
    }
#pragma unroll
    for (int off = 32; off > 0; off >>= 1) s += __shfl_down(s, off);
    __shared__ int ws[4];
    int lane = threadIdx.x & 63, wid = threadIdx.x >> 6;
    if (lane == 0) ws[wid] = s;
    __syncthreads();
    if (threadIdx.x == 0) blockSums[blockIdx.x] = ws[0] + ws[1] + ws[2] + ws[3];
}

__global__ void scan_offsets(const int* __restrict__ blockSums,
                             int* __restrict__ blockOff, int* __restrict__ rowptr)
{
    int lane = threadIdx.x;  // 64 threads
    int v = (lane < NB_SCAN) ? blockSums[lane] : 0;
    int inc = v;
#pragma unroll
    for (int off = 1; off < 64; off <<= 1) {
        int n = __shfl_up(inc, off);
        if (lane >= off) inc += n;
    }
    if (lane < NB_SCAN) blockOff[lane] = inc - v;
    if (lane == 63) rowptr[NN] = EE;
}

__global__ void __launch_bounds__(256) deg_scan_write(
    const int* __restrict__ deg, const int* __restrict__ blockOff,
    int* __restrict__ rowptr, int* __restrict__ cursor)
{
    __shared__ int warpSums[4];
    int base = blockIdx.x * SCAN_CHUNK + threadIdx.x * 8;
    int v[8];
    int s = 0;
#pragma unroll
    for (int i = 0; i < 8; ++i) {
        int idx = base + i;
        v[i] = (idx < NN) ? deg[idx] : 0;
        s += v[i];
    }
    int lane = threadIdx.x & 63, wid = threadIdx.x >> 6;
    int inc = s;
#pragma unroll
    for (int off = 1; off < 64; off <<= 1) {
        int n = __shfl_up(inc, off);
        if (lane >= off) inc += n;
    }
    if (lane == 63) warpSums[wid] = inc;
    __syncthreads();
    int wofs = 0;
#pragma unroll
    for (int w = 0; w < 4; ++w)
        if (w < wid) wofs += warpSums[w];
    int exc = blockOff[blockIdx.x] + wofs + (inc - s);
#pragma unroll
    for (int i = 0; i < 8; ++i) {
        int idx = base + i;
        if (idx < NN) { rowptr[idx] = exc; cursor[idx] = exc; }
        exc += v[i];
    }
}

__global__ void __launch_bounds__(256) fill_csr(
    const int* __restrict__ src, const int* __restrict__ dst,
    int* __restrict__ cursor, int* __restrict__ col)
{
    int e = blockIdx.x * 256 + threadIdx.x;
    if (e < EE) {
        int d = dst[e];
        int pos = atomicAdd(&cursor[d], 1);
        col[pos] = src[e];
    }
}

// ===========================================================================
// Gather aggregation: agg[i] = h[i] + sum_{nbr} h[nbr]
// Block = 256 threads = 8 nodes x 32 threads; each thread owns 4 channels.
// ===========================================================================
__global__ void __launch_bounds__(256) gather_agg(
    const float* __restrict__ h, const int* __restrict__ rowptr,
    const int* __restrict__ col, float* __restrict__ agg)
{
    int node = blockIdx.x * 8 + (threadIdx.x >> 5);
    int c4 = (threadIdx.x & 31) * 4;
    const float4* hp = (const float4*)h;
    int vidx = node * 32 + (c4 >> 2);
    float4 s = hp[vidx];
    int beg = rowptr[node], end = rowptr[node + 1];
    int j = beg;
    // unroll-2 with independent accumulators
    float4 s2 = make_float4(0.f, 0.f, 0.f, 0.f);
    for (; j + 1 < end; j += 2) {
        int n0 = col[j], n1 = col[j + 1];
        float4 a = hp[n0 * 32 + (c4 >> 2)];
        float4 b = hp[n1 * 32 + (c4 >> 2)];
        s.x += a.x; s.y += a.y; s.z += a.z; s.w += a.w;
        s2.x += b.x; s2.y += b.y; s2.z += b.z; s2.w += b.w;
    }
    if (j < end) {
        int n0 = col[j];
        float4 a = hp[n0 * 32 + (c4 >> 2)];
        s.x += a.x; s.y += a.y; s.z += a.z; s.w += a.w;
    }
    s.x += s2.x; s.y += s2.y; s.z += s2.z; s.w += s2.w;
    ((float4*)agg)[vidx] = s;
}

// ===========================================================================
// Fused GIN MLP: hout = elu( relu( hin @ wa + ba ) @ wb + bb )
// ===========================================================================
__global__ void __launch_bounds__(256) mlp_kernel(
    const float* __restrict__ hin,
    const float* __restrict__ wa, const float* __restrict__ ba,
    const float* __restrict__ wb, const float* __restrict__ bb,
    float* __restrict__ hout)
{
    __shared__ float At[CC][TM + 1];
    __shared__ float Tt[CC][TM + 1];

    const int tid  = threadIdx.x;
    const int row0 = blockIdx.x * TM;

    for (int idx = tid; idx < TM * CC; idx += 256) {
        int r = idx >> 7;
        int k = idx & (CC - 1);
        At[k][r] = hin[(row0 + r) * CC + k];
    }
    __syncthreads();

    const int cg = tid & 31;
    const int rg = tid >> 5;
    const int c0 = cg * 4;
    const int r0 = rg * 4;

    float acc[4][4];
#pragma unroll
    for (int i = 0; i < 4; ++i)
#pragma unroll
        for (int j = 0; j < 4; ++j) acc[i][j] = 0.f;

#pragma unroll 4
    for (int k = 0; k < CC; ++k) {
        const float4 w = *(const float4*)&wa[k * CC + c0];
        const float a0 = At[k][r0 + 0];
        const float a1 = At[k][r0 + 1];
        const float a2 = At[k][r0 + 2];
        const float a3 = At[k][r0 + 3];
        acc[0][0] += a0 * w.x; acc[0][1] += a0 * w.y; acc[0][2] += a0 * w.z; acc[0][3] += a0 * w.w;
        acc[1][0] += a1 * w.x; acc[1][1] += a1 * w.y; acc[1][2] += a1 * w.z; acc[1][3] += a1 * w.w;
        acc[2][0] += a2 * w.x; acc[2][1] += a2 * w.y; acc[2][2] += a2 * w.z; acc[2][3] += a2 * w.w;
        acc[3][0] += a3 * w.x; acc[3][1] += a3 * w.y; acc[3][2] += a3 * w.z; acc[3][3] += a3 * w.w;
    }
    {
        const float4 bias = *(const float4*)&ba[c0];
#pragma unroll
        for (int r = 0; r < 4; ++r) {
            Tt[c0 + 0][r0 + r] = fmaxf(acc[r][0] + bias.x, 0.f);
            Tt[c0 + 1][r0 + r] = fmaxf(acc[r][1] + bias.y, 0.f);
            Tt[c0 + 2][r0 + r] = fmaxf(acc[r][2] + bias.z, 0.f);
            Tt[c0 + 3][r0 + r] = fmaxf(acc[r][3] + bias.w, 0.f);
        }
    }
    __syncthreads();

#pragma unroll
    for (int i = 0; i < 4; ++i)
#pragma unroll
        for (int j = 0; j < 4; ++j) acc[i][j] = 0.f;

#pragma unroll 4
    for (int k = 0; k < CC; ++k) {
        const float4 w = *(const float4*)&wb[k * CC + c0];
        const float a0 = Tt[k][r0 + 0];
        const float a1 = Tt[k][r0 + 1];
        const float a2 = Tt[k][r0 + 2];
        const float a3 = Tt[k][r0 + 3];
        acc[0][0] += a0 * w.x; acc[0][1] += a0 * w.y; acc[0][2] += a0 * w.z; acc[0][3] += a0 * w.w;
        acc[1][0] += a1 * w.x; acc[1][1] += a1 * w.y; acc[1][2] += a1 * w.z; acc[1][3] += a1 * w.w;
        acc[2][0] += a2 * w.x; acc[2][1] += a2 * w.y; acc[2][2] += a2 * w.z; acc[2][3] += a2 * w.w;
        acc[3][0] += a3 * w.x; acc[3][1] += a3 * w.y; acc[3][2] += a3 * w.z; acc[3][3] += a3 * w.w;
    }
    {
        const float4 bias = *(const float4*)&bb[c0];
#pragma unroll
        for (int r = 0; r < 4; ++r) {
            float v0 = acc[r][0] + bias.x;
            float v1 = acc[r][1] + bias.y;
            float v2 = acc[r][2] + bias.z;
            float v3 = acc[r][3] + bias.w;
            float4 o;
            o.x = v0 > 0.f ? v0 : expm1f(v0);
            o.y = v1 > 0.f ? v1 : expm1f(v1);
            o.z = v2 > 0.f ? v2 : expm1f(v2);
            o.w = v3 > 0.f ? v3 : expm1f(v3);
            *(float4*)&hout[(row0 + r0 + r) * CC + c0] = o;
        }
    }
}

// ===========================================================================
// Final head: out[i] = sigmoid(dot(h[i], lin_w) + lin_b). One wave per node.
// ===========================================================================
__global__ void __launch_bounds__(256) final_kernel(
    const float* __restrict__ h, const float* __restrict__ lin_w,
    const float* __restrict__ lin_b, float* __restrict__ out)
{
    int wave = (blockIdx.x * 256 + threadIdx.x) >> 6;
    int lane = threadIdx.x & 63;
    if (wave >= NN) return;
    const float2 v = *(const float2*)&h[wave * CC + lane * 2];
    const float2 w = *(const float2*)&lin_w[lane * 2];
    float s = v.x * w.x + v.y * w.y;
#pragma unroll
    for (int off = 32; off > 0; off >>= 1) s += __shfl_down(s, off);
    if (lane == 0) {
        float z = s + lin_b[0];
        out[wave] = 1.f / (1.f + expf(-z));
    }
}

extern "C" void kernel_launch(void* const* d_in, const int* in_sizes, int n_in,
                              void* d_out, int out_size, void* d_ws, size_t ws_size,
                              hipStream_t stream) {
    const float* x   = (const float*)d_in[0];
    const int*   ei  = (const int*)d_in[1];      // [2][E]: row0=src, row1=dst
    const int*   src = ei;
    const int*   dst = ei + EE;
    const float* w0a = (const float*)d_in[2];
    const float* b0a = (const float*)d_in[3];
    const float* w0b = (const float*)d_in[4];
    const float* b0b = (const float*)d_in[5];
    const float* w1a = (const float*)d_in[6];
    const float* b1a = (const float*)d_in[7];
    const float* w1b = (const float*)d_in[8];
    const float* b1b = (const float*)d_in[9];
    const float* w2a = (const float*)d_in[10];
    const float* b2a = (const float*)d_in[11];
    const float* w2b = (const float*)d_in[12];
    const float* b2b = (const float*)d_in[13];
    const float* lw  = (const float*)d_in[14];
    const float* lb  = (const float*)d_in[15];
    float* outp = (float*)d_out;

    // workspace layout
    float* hA   = (float*)d_ws;                     // N*CC floats
    float* agg  = hA + (size_t)NN * CC;             // N*CC floats
    int*   col  = (int*)(agg + (size_t)NN * CC);    // EE ints
    int*   rowptr    = col + EE;                    // NN+1
    int*   cursor    = rowptr + NN + 1;             // NN
    int*   deg       = cursor + NN;                 // NN
    int*   blockSums = deg + NN;                    // NB_SCAN
    int*   blockOff  = blockSums + NB_SCAN;         // NB_SCAN

    const int edgeBlocks = EE / 256;   // 6250
    const int mlpBlocks  = NN / TM;    // 3125
    const int aggBlocks  = NN / 8;     // 12500
    const int finalBlocks = (NN * 64) / 256;

    // ---- CSR build (once, reused by all 3 layers) ----
    hipMemsetAsync(deg, 0, NN * sizeof(int), stream);
    hist_kernel<<<edgeBlocks, 256, 0, stream>>>(dst, deg);
    deg_block_reduce<<<NB_SCAN, 256, 0, stream>>>(deg, blockSums);
    scan_offsets<<<1, 64, 0, stream>>>(blockSums, blockOff, rowptr);
    deg_scan_write<<<NB_SCAN, 256, 0, stream>>>(deg, blockOff, rowptr, cursor);
    fill_csr<<<edgeBlocks, 256, 0, stream>>>(src, dst, cursor, col);

    // ---- layer 1 ----
    gather_agg<<<aggBlocks, 256, 0, stream>>>(x, rowptr, col, agg);
    mlp_kernel<<<mlpBlocks, 256, 0, stream>>>(agg, w0a, b0a, w0b, b0b, hA);

    // ---- layer 2 ----
    gather_agg<<<aggBlocks, 256, 0, stream>>>(hA, rowptr, col, agg);
    mlp_kernel<<<mlpBlocks, 256, 0, stream>>>(agg, w1a, b1a, w1b, b1b, hA);

    // ---- layer 3 ----
    gather_agg<<<aggBlocks, 256, 0, stream>>>(hA, rowptr, col, agg);
    mlp_kernel<<<mlpBlocks, 256, 0, stream>>>(agg, w2a, b2a, w2b, b2b, hA);

    // ---- head ----
    final_kernel<<<finalBlocks, 256, 0, stream>>>(hA, lw, lb, outp);
}

// Round 3
// 731.486 us; speedup vs baseline: 3.5434x; 1.4550x over previous
//
#include <hip/hip_runtime.h>
#include <hip/hip_bf16.h>
#include <math.h>

#define NN 100000
#define CC 128
#define EE 1600000
#define SCAN_CHUNK 2048
#define NB_SCAN ((NN + SCAN_CHUNK - 1) / SCAN_CHUNK)  // 49

typedef short bf16x8 __attribute__((ext_vector_type(8)));
typedef float f32x4  __attribute__((ext_vector_type(4)));

#define APAD 136   // ushort stride for At rows (272 B, 16B-aligned)
#define TPAD 132   // float stride for Tt rows (528 B, 16B-aligned)

__device__ __forceinline__ ushort f2bf(float f) {
    __hip_bfloat16 h = __float2bfloat16(f);   // RNE
    return __builtin_bit_cast(ushort, h);
}
__device__ __forceinline__ float bf2f(ushort u) {
    return __builtin_bit_cast(float, ((unsigned int)u) << 16);
}

// ===========================================================================
// CSR build
// ===========================================================================
__global__ void __launch_bounds__(256) hist_kernel(
    const int* __restrict__ dst, int* __restrict__ deg)
{
    int e = blockIdx.x * 256 + threadIdx.x;
    if (e < EE) atomicAdd(&deg[dst[e]], 1);
}

__global__ void __launch_bounds__(256) deg_block_reduce(
    const int* __restrict__ deg, int* __restrict__ blockSums)
{
    int base = blockIdx.x * SCAN_CHUNK + threadIdx.x * 8;
    int s = 0;
#pragma unroll
    for (int i = 0; i < 8; ++i) {
        int idx = base + i;
        if (idx < NN) s += deg[idx];
    }
#pragma unroll
    for (int off = 32; off > 0; off >>= 1) s += __shfl_down(s, off);
    __shared__ int ws[4];
    int lane = threadIdx.x & 63, wid = threadIdx.x >> 6;
    if (lane == 0) ws[wid] = s;
    __syncthreads();
    if (threadIdx.x == 0) blockSums[blockIdx.x] = ws[0] + ws[1] + ws[2] + ws[3];
}

__global__ void scan_offsets(const int* __restrict__ blockSums,
                             int* __restrict__ blockOff, int* __restrict__ rowptr)
{
    int lane = threadIdx.x;  // 64 threads
    int v = (lane < NB_SCAN) ? blockSums[lane] : 0;
    int inc = v;
#pragma unroll
    for (int off = 1; off < 64; off <<= 1) {
        int n = __shfl_up(inc, off);
        if (lane >= off) inc += n;
    }
    if (lane < NB_SCAN) blockOff[lane] = inc - v;
    if (lane == 63) rowptr[NN] = EE;
}

__global__ void __launch_bounds__(256) deg_scan_write(
    const int* __restrict__ deg, const int* __restrict__ blockOff,
    int* __restrict__ rowptr, int* __restrict__ cursor)
{
    __shared__ int warpSums[4];
    int base = blockIdx.x * SCAN_CHUNK + threadIdx.x * 8;
    int v[8];
    int s = 0;
#pragma unroll
    for (int i = 0; i < 8; ++i) {
        int idx = base + i;
        v[i] = (idx < NN) ? deg[idx] : 0;
        s += v[i];
    }
    int lane = threadIdx.x & 63, wid = threadIdx.x >> 6;
    int inc = s;
#pragma unroll
    for (int off = 1; off < 64; off <<= 1) {
        int n = __shfl_up(inc, off);
        if (lane >= off) inc += n;
    }
    if (lane == 63) warpSums[wid] = inc;
    __syncthreads();
    int wofs = 0;
#pragma unroll
    for (int w = 0; w < 4; ++w)
        if (w < wid) wofs += warpSums[w];
    int exc = blockOff[blockIdx.x] + wofs + (inc - s);
#pragma unroll
    for (int i = 0; i < 8; ++i) {
        int idx = base + i;
        if (idx < NN) { rowptr[idx] = exc; cursor[idx] = exc; }
        exc += v[i];
    }
}

__global__ void __launch_bounds__(256) fill_csr(
    const int* __restrict__ src, const int* __restrict__ dst,
    int* __restrict__ cursor, int* __restrict__ col)
{
    int e = blockIdx.x * 256 + threadIdx.x;
    if (e < EE) {
        int d = dst[e];
        int pos = atomicAdd(&cursor[d], 1);
        col[pos] = src[e];
    }
}

// ===========================================================================
// Conversions
// ===========================================================================
__global__ void __launch_bounds__(256) convert_x_kernel(
    const float* __restrict__ x, ushort* __restrict__ xb)
{
    int i = blockIdx.x * 256 + threadIdx.x;   // float4 groups; NN*CC/4 total
    float4 v = ((const float4*)x)[i];
    ushort4 o;
    o.x = f2bf(v.x); o.y = f2bf(v.y); o.z = f2bf(v.z); o.w = f2bf(v.w);
    ((ushort4*)xb)[i] = o;
}

// w [128][128] fp32 row-major (k,n) -> wt [128][128] bf16 (n,k)
__global__ void __launch_bounds__(256) convert_w_kernel(
    const float* __restrict__ w, ushort* __restrict__ wt)
{
    int i = blockIdx.x * 256 + threadIdx.x;  // 16384
    int k = i >> 7, n = i & 127;
    wt[n * 128 + k] = f2bf(w[k * 128 + n]);
}

// ===========================================================================
// Gather aggregation (bf16): agg[i] = h[i] + sum_{nbr} h[nbr]
// 8 nodes per block; 32 threads/node; 4 channels/thread (8 B loads).
// ===========================================================================
__global__ void __launch_bounds__(256) gather_agg(
    const ushort* __restrict__ h, const int* __restrict__ rowptr,
    const int* __restrict__ col, ushort* __restrict__ agg)
{
    int node = blockIdx.x * 8 + (threadIdx.x >> 5);
    int c = (threadIdx.x & 31) * 4;
    const ushort4* hp = (const ushort4*)h;
    int vidx = node * 32 + (c >> 2);

    ushort4 self = hp[vidx];
    float s0 = bf2f(self.x), s1 = bf2f(self.y), s2 = bf2f(self.z), s3 = bf2f(self.w);
    float t0 = 0.f, t1 = 0.f, t2 = 0.f, t3 = 0.f;

    int beg = rowptr[node], end = rowptr[node + 1];
    int j = beg;
    for (; j + 1 < end; j += 2) {
        int n0 = col[j], n1 = col[j + 1];
        ushort4 a = hp[n0 * 32 + (c >> 2)];
        ushort4 b = hp[n1 * 32 + (c >> 2)];
        s0 += bf2f(a.x); s1 += bf2f(a.y); s2 += bf2f(a.z); s3 += bf2f(a.w);
        t0 += bf2f(b.x); t1 += bf2f(b.y); t2 += bf2f(b.z); t3 += bf2f(b.w);
    }
    if (j < end) {
        int n0 = col[j];
        ushort4 a = hp[n0 * 32 + (c >> 2)];
        s0 += bf2f(a.x); s1 += bf2f(a.y); s2 += bf2f(a.z); s3 += bf2f(a.w);
    }
    s0 += t0; s1 += t1; s2 += t2; s3 += t3;
    ushort4 o;
    o.x = f2bf(s0); o.y = f2bf(s1); o.z = f2bf(s2); o.w = f2bf(s3);
    ((ushort4*)agg)[vidx] = o;
}

// ===========================================================================
// MFMA MLP: hout = elu( relu( hin @ Wa + ba ) @ Wb + bb )
// Block = 256 thr = 4 waves; tile 64 rows x 128 cols; K=128.
// Weights pre-transposed bf16 WT[n][k]. If FUSE_HEAD, computes
// out[i] = sigmoid(dot(elu_row, lw) + lb) instead of storing hout.
// ===========================================================================
template <bool FUSE_HEAD>
__global__ void __launch_bounds__(256) mlp_mfma(
    const ushort* __restrict__ hin,
    const ushort* __restrict__ waT, const float* __restrict__ ba,
    const ushort* __restrict__ wbT, const float* __restrict__ bb,
    ushort* __restrict__ hout,
    const float* __restrict__ lw, const float* __restrict__ lb,
    float* __restrict__ out)
{
    __shared__ ushort At[64 * APAD];  // bf16 activations, padded
    __shared__ float  Tt[64 * TPAD];  // fp32 stage-1 output / stage-2 output

    const int tid  = threadIdx.x;
    const int row0 = blockIdx.x * 64;

    // ---- stage A into LDS: 64 rows x 128 bf16, ushort8 (16B) loads ----
#pragma unroll
    for (int i = 0; i < 4; ++i) {
        int v  = tid + i * 256;
        int r  = v >> 4;        // 0..63
        int kv = v & 15;        // 16B chunk within row
        int grow = row0 + r;
        bf16x8 val = {0, 0, 0, 0, 0, 0, 0, 0};
        if (grow < NN) val = *(const bf16x8*)&hin[grow * CC + kv * 8];
        *(bf16x8*)&At[r * APAD + kv * 8] = val;
    }
    __syncthreads();

    const int wave = tid >> 6;
    const int lane = tid & 63;
    const int m0   = wave * 16;
    const int quad = lane >> 4;
    const int l16  = lane & 15;

    // ---- stage 1: T = relu(A @ Wa + ba) ----
    bf16x8 afrag[4];
#pragma unroll
    for (int kk = 0; kk < 4; ++kk)
        afrag[kk] = *(const bf16x8*)&At[(m0 + l16) * APAD + kk * 32 + quad * 8];

    f32x4 acc[8];
#pragma unroll
    for (int nt = 0; nt < 8; ++nt) acc[nt] = (f32x4){0.f, 0.f, 0.f, 0.f};

#pragma unroll
    for (int kk = 0; kk < 4; ++kk) {
#pragma unroll
        for (int nt = 0; nt < 8; ++nt) {
            bf16x8 bfrag = *(const bf16x8*)&waT[(nt * 16 + l16) * CC + kk * 32 + quad * 8];
            acc[nt] = __builtin_amdgcn_mfma_f32_16x16x32_bf16(afrag[kk], bfrag, acc[nt], 0, 0, 0);
        }
    }

#pragma unroll
    for (int nt = 0; nt < 8; ++nt) {
        int colc = nt * 16 + l16;
        float bias = ba[colc];
#pragma unroll
        for (int r = 0; r < 4; ++r) {
            float v = acc[nt][r] + bias;
            Tt[(m0 + quad * 4 + r) * TPAD + colc] = fmaxf(v, 0.f);
        }
    }
    __syncthreads();

    // ---- stage 2 A-fragments from Tt (cvt fp32 -> bf16) ----
    bf16x8 a2[4];
#pragma unroll
    for (int kk = 0; kk < 4; ++kk) {
        const float* tp = &Tt[(m0 + l16) * TPAD + kk * 32 + quad * 8];
        float4 t0 = *(const float4*)tp;
        float4 t1 = *(const float4*)(tp + 4);
        bf16x8 f;
        f[0] = (short)f2bf(t0.x); f[1] = (short)f2bf(t0.y);
        f[2] = (short)f2bf(t0.z); f[3] = (short)f2bf(t0.w);
        f[4] = (short)f2bf(t1.x); f[5] = (short)f2bf(t1.y);
        f[6] = (short)f2bf(t1.z); f[7] = (short)f2bf(t1.w);
        a2[kk] = f;
    }
    __syncthreads();   // all waves done reading Tt before stage-2 epilogue writes

    f32x4 acc2[8];
#pragma unroll
    for (int nt = 0; nt < 8; ++nt) acc2[nt] = (f32x4){0.f, 0.f, 0.f, 0.f};

#pragma unroll
    for (int kk = 0; kk < 4; ++kk) {
#pragma unroll
        for (int nt = 0; nt < 8; ++nt) {
            bf16x8 bfrag = *(const bf16x8*)&wbT[(nt * 16 + l16) * CC + kk * 32 + quad * 8];
            acc2[nt] = __builtin_amdgcn_mfma_f32_16x16x32_bf16(a2[kk], bfrag, acc2[nt], 0, 0, 0);
        }
    }

    if (FUSE_HEAD) {
        // per-row dot with lw across the 128 cols, then sigmoid
        float part[4] = {0.f, 0.f, 0.f, 0.f};
#pragma unroll
        for (int nt = 0; nt < 8; ++nt) {
            int colc = nt * 16 + l16;
            float bias = bb[colc];
            float w = lw[colc];
#pragma unroll
            for (int r = 0; r < 4; ++r) {
                float v = acc2[nt][r] + bias;
                v = v > 0.f ? v : expm1f(v);
                part[r] += v * w;
            }
        }
#pragma unroll
        for (int r = 0; r < 4; ++r) {
#pragma unroll
            for (int off = 8; off > 0; off >>= 1)
                part[r] += __shfl_xor(part[r], off);
        }
        if (l16 == 0) {
            float lbv = lb[0];
#pragma unroll
            for (int r = 0; r < 4; ++r) {
                int grow = row0 + m0 + quad * 4 + r;
                if (grow < NN) {
                    float z = part[r] + lbv;
                    out[grow] = 1.f / (1.f + expf(-z));
                }
            }
        }
    } else {
        // elu epilogue -> Tt (fp32) -> coalesced bf16 store
#pragma unroll
        for (int nt = 0; nt < 8; ++nt) {
            int colc = nt * 16 + l16;
            float bias = bb[colc];
#pragma unroll
            for (int r = 0; r < 4; ++r) {
                float v = acc2[nt][r] + bias;
                Tt[(m0 + quad * 4 + r) * TPAD + colc] = v > 0.f ? v : expm1f(v);
            }
        }
        __syncthreads();
#pragma unroll
        for (int i = 0; i < 8; ++i) {
            int v  = tid + i * 256;
            int r  = v >> 5;          // 0..63
            int cv = v & 31;          // float4 chunk within row
            int grow = row0 + r;
            if (grow < NN) {
                float4 t = *(const float4*)&Tt[r * TPAD + cv * 4];
                ushort4 o;
                o.x = f2bf(t.x); o.y = f2bf(t.y); o.z = f2bf(t.z); o.w = f2bf(t.w);
                *(ushort4*)&hout[grow * CC + cv * 4] = o;
            }
        }
    }
}

extern "C" void kernel_launch(void* const* d_in, const int* in_sizes, int n_in,
                              void* d_out, int out_size, void* d_ws, size_t ws_size,
                              hipStream_t stream) {
    const float* x   = (const float*)d_in[0];
    const int*   ei  = (const int*)d_in[1];
    const int*   src = ei;
    const int*   dst = ei + EE;
    const float* w0a = (const float*)d_in[2];
    const float* b0a = (const float*)d_in[3];
    const float* w0b = (const float*)d_in[4];
    const float* b0b = (const float*)d_in[5];
    const float* w1a = (const float*)d_in[6];
    const float* b1a = (const float*)d_in[7];
    const float* w1b = (const float*)d_in[8];
    const float* b1b = (const float*)d_in[9];
    const float* w2a = (const float*)d_in[10];
    const float* b2a = (const float*)d_in[11];
    const float* w2b = (const float*)d_in[12];
    const float* b2b = (const float*)d_in[13];
    const float* lw  = (const float*)d_in[14];
    const float* lb  = (const float*)d_in[15];
    float* outp = (float*)d_out;

    // workspace layout
    ushort* xb  = (ushort*)d_ws;                      // N*CC bf16
    ushort* agg = xb + (size_t)NN * CC;               // N*CC bf16
    ushort* hb  = agg + (size_t)NN * CC;              // N*CC bf16
    ushort* wT  = hb + (size_t)NN * CC;               // 6 * 128*128 bf16
    int* col    = (int*)(wT + 6 * CC * CC);           // EE
    int* rowptr    = col + EE;                        // NN+1
    int* cursor    = rowptr + NN + 1;                 // NN
    int* deg       = cursor + NN;                     // NN
    int* blockSums = deg + NN;                        // NB_SCAN
    int* blockOff  = blockSums + NB_SCAN;             // NB_SCAN

    ushort* w0aT = wT;
    ushort* w0bT = wT + 1 * CC * CC;
    ushort* w1aT = wT + 2 * CC * CC;
    ushort* w1bT = wT + 3 * CC * CC;
    ushort* w2aT = wT + 4 * CC * CC;
    ushort* w2bT = wT + 5 * CC * CC;

    const int edgeBlocks = EE / 256;
    const int aggBlocks  = NN / 8;
    const int mlpBlocks  = (NN + 63) / 64;   // 1563
    const int cvtXBlocks = (NN * CC / 4) / 256;

    // ---- conversions ----
    convert_x_kernel<<<cvtXBlocks, 256, 0, stream>>>(x, xb);
    convert_w_kernel<<<64, 256, 0, stream>>>(w0a, w0aT);
    convert_w_kernel<<<64, 256, 0, stream>>>(w0b, w0bT);
    convert_w_kernel<<<64, 256, 0, stream>>>(w1a, w1aT);
    convert_w_kernel<<<64, 256, 0, stream>>>(w1b, w1bT);
    convert_w_kernel<<<64, 256, 0, stream>>>(w2a, w2aT);
    convert_w_kernel<<<64, 256, 0, stream>>>(w2b, w2bT);

    // ---- CSR build ----
    hipMemsetAsync(deg, 0, NN * sizeof(int), stream);
    hist_kernel<<<edgeBlocks, 256, 0, stream>>>(dst, deg);
    deg_block_reduce<<<NB_SCAN, 256, 0, stream>>>(deg, blockSums);
    scan_offsets<<<1, 64, 0, stream>>>(blockSums, blockOff, rowptr);
    deg_scan_write<<<NB_SCAN, 256, 0, stream>>>(deg, blockOff, rowptr, cursor);
    fill_csr<<<edgeBlocks, 256, 0, stream>>>(src, dst, cursor, col);

    // ---- layer 1 ----
    gather_agg<<<aggBlocks, 256, 0, stream>>>(xb, rowptr, col, agg);
    mlp_mfma<false><<<mlpBlocks, 256, 0, stream>>>(agg, w0aT, b0a, w0bT, b0b, hb,
                                                   nullptr, nullptr, nullptr);
    // ---- layer 2 ----
    gather_agg<<<aggBlocks, 256, 0, stream>>>(hb, rowptr, col, agg);
    mlp_mfma<false><<<mlpBlocks, 256, 0, stream>>>(agg, w1aT, b1a, w1bT, b1b, hb,
                                                   nullptr, nullptr, nullptr);
    // ---- layer 3 + fused head ----
    gather_agg<<<aggBlocks, 256, 0, stream>>>(hb, rowptr, col, agg);
    mlp_mfma<true><<<mlpBlocks, 256, 0, stream>>>(agg, w2aT, b2a, w2bT, b2b, nullptr,
                                                  lw, lb, outp);
}